// Round 6
// baseline (168.304 us; speedup 1.0000x reference)
//
#include <hip/hip_runtime.h>

// ACT-LSTM forward, MI355X (gfx950).
// I=1024, H=2048, O=1024, 4H=8192, MAX_STEPS=20, thresh=0.99.
//
// Round-5 post-mortem: 167.7 us total = ~135 us fixed harness overhead
// (input restore + 268MB ws poison fills + graph replay) + ~33 us kernel
// chain. Kernel memory floor: step0 ~100MB cold (~16 us), step1 67MB
// L3-warm (~7 us), final ~3 us => ~26-29 us incl. dispatch gaps.
//
// This round: 4 -> 3 dispatches. fb_final recomputes the halt decisions
// deterministically (identical reduction order in every block; bit-identical
// to fb_step1's) and selects t* locally — the separate fb_tail dispatch is
// gone. The never-taken continuation (steps 2..19) lives in fb_final's
// block 0 as a correct serial fallback.
//
//   fb_step0  z = W_ih@[1,x]+biases fused with step-0 W_hh matvec
//   fb_step1  halt-check(step0) prologue + step-1 W_hh matvec
//   fb_final  halt-check(step0,1) + W_out matvec + h/c/ponder writes
//             (+ dead serial path for steps 2..19 in block 0)
//
// Data: p ~= sigmoid(1) ~= 0.73/step -> cum after step1 ~= 1.46 >= 0.99
// (margin 0.47) -> t* = 1: exactly 2 real matvec steps.
// Straight-through Binarize selects EXACTLY step t* in fp32
// (x+(0-x)==0; Sterbenz gives soft+(1-soft)==1 since soft<2), ponder == t*.

#define NB    1024      // blocks; block b owns h-columns {2b, 2b+1}
#define BT    256       // 4 waves; wave w == gate w (i,f,g,o)
#define CPB   2
#define HDIM  2048
#define IDIM  1024
#define ODIM  1024
#define G4    8192
#define MAXS  20

static_assert(NB * CPB == HDIM, "columns must tile H");

__device__ __attribute__((aligned(16))) float g_h[2][HDIM];  // dbuf hidden
__device__ float g_c[HDIM];        // cell state
__device__ float g_part[2][NB];    // dbuf halting partials (one per block)
__device__ float g_z[G4];          // z = W_ih[:,1:]@x + b_ih + b_hh

__device__ __forceinline__ float wave_reduce(float v) {
  #pragma unroll
  for (int off = 32; off; off >>= 1) v += __shfl_xor(v, off, 64);
  return v;  // full 64-lane sum on all lanes
}
__device__ __forceinline__ float sigf(float v) {
  return 1.0f / (1.0f + expf(-v));
}
__device__ __forceinline__ float dot4(float4 a, float4 b) {
  return a.x * b.x + a.y * b.y + a.z * b.z + a.w * b.w;
}

// ---- shared inner body: recurrent matvec + cell update for one step ------
__device__ __forceinline__ void step_body(
    int cur, bool first, const float4* __restrict__ hsrc,
    const float* __restrict__ c_in, const float* __restrict__ W_hh,
    const float* __restrict__ w_halt, float za, float zb)
{
  const int tid  = threadIdx.x;
  const int w    = tid >> 6;
  const int lane = tid & 63;
  const int j0   = blockIdx.x * CPB;
  const int ra   = w * HDIM + j0;
  const int rb   = ra + 1;

  __shared__ float4 hs[HDIM / 4];   // 8 KB h stage
  __shared__ float  gsm[4][CPB];
  __shared__ float  pvs[CPB];

  hs[tid]       = hsrc[tid];
  hs[tid + 256] = hsrc[tid + 256];
  __syncthreads();

  const float4* Whh4 = reinterpret_cast<const float4*>(W_hh);
  const float4* WA4  = Whh4 + (size_t)ra * (HDIM / 4);
  const float4* WB4  = Whh4 + (size_t)rb * (HDIM / 4);
  float4 wa[8], wb[8];                       // 16 float4 loads in flight
  #pragma unroll
  for (int t = 0; t < 8; ++t) {
    const int idx = t * 64 + lane;
    wa[t] = WA4[idx];
    wb[t] = WB4[idx];
  }
  float sa = 0.f, sb = 0.f;
  #pragma unroll
  for (int t = 0; t < 8; ++t) {
    const float4 hv = hs[t * 64 + lane];
    sa += dot4(wa[t], hv);
    sb += dot4(wb[t], hv);
  }
  sa = wave_reduce(sa);
  sb = wave_reduce(sb);
  if (lane == 0) {
    gsm[w][0] = za + sa;
    gsm[w][1] = zb + sb;
  }
  __syncthreads();

  if (tid < CPB) {
    const int j = j0 + tid;
    const float gi = gsm[0][tid], gf = gsm[1][tid];
    const float gg = gsm[2][tid], go = gsm[3][tid];
    const float co = first ? c_in[j] : g_c[j];
    const float cn = sigf(gf) * co + sigf(gi) * tanhf(gg);
    const float hn = sigf(go) * tanhf(cn);
    g_c[j]      = cn;
    g_h[cur][j] = hn;
    pvs[tid]    = w_halt[j] * hn;
  }
  __syncthreads();
  if (tid == 0) g_part[cur][blockIdx.x] = pvs[0] + pvs[1];
}

// ---- dispatch 1: z-phase fused with step-0 matvec ------------------------
__global__ __launch_bounds__(BT, 4) void fb_step0(
    const float* __restrict__ x,    const float* __restrict__ h_in,
    const float* __restrict__ c_in, const float* __restrict__ W_ih,
    const float* __restrict__ W_hh, const float* __restrict__ b_ih,
    const float* __restrict__ b_hh, const float* __restrict__ w_halt)
{
  const int tid  = threadIdx.x;
  const int w    = tid >> 6;
  const int lane = tid & 63;
  const int j0   = blockIdx.x * CPB;
  const int ra   = w * HDIM + j0;
  const int rb   = ra + 1;

  const float* Wa = W_ih + (size_t)ra * (IDIM + 1);
  const float* Wb = W_ih + (size_t)rb * (IDIM + 1);
  float za = 0.f, zb = 0.f;
  #pragma unroll
  for (int k = 0; k < 2; ++k) {
    float xv[8], va[8], vb[8];                 // 24 loads in flight
    #pragma unroll
    for (int t = 0; t < 8; ++t) {
      const int c = (k * 8 + t) * 64 + lane;
      xv[t] = x[c];
      va[t] = Wa[1 + c];
      vb[t] = Wb[1 + c];
    }
    #pragma unroll
    for (int t = 0; t < 8; ++t) { za += va[t] * xv[t]; zb += vb[t] * xv[t]; }
  }
  za = wave_reduce(za) + b_ih[ra] + b_hh[ra];
  zb = wave_reduce(zb) + b_ih[rb] + b_hh[rb];
  if (lane == 0) {           // persist for steps 1..19
    g_z[ra] = za;
    g_z[rb] = zb;
  }
  step_body(/*cur=*/0, /*first=*/true,
            reinterpret_cast<const float4*>(h_in), c_in, W_hh, w_halt,
            za + Wa[0], zb + Wb[0]);           // + flag column on step 0
}

// ---- dispatch 2: halt-check(step0) + step-1 matvec -----------------------
__global__ __launch_bounds__(BT, 4) void fb_step1(
    const float* __restrict__ c_in, const float* __restrict__ W_hh,
    const float* __restrict__ w_halt, const float* __restrict__ b_halt)
{
  const int tid  = threadIdx.x;
  const int w    = tid >> 6;
  const int lane = tid & 63;

  // halt decision for step 0: identical deterministic sum in every block
  __shared__ float red[4];
  float ps = g_part[0][tid]       + g_part[0][tid + 256]
           + g_part[0][tid + 512] + g_part[0][tid + 768];
  ps = wave_reduce(ps);
  if (lane == 0) red[w] = ps;
  __syncthreads();
  const float p0 = sigf((red[0] + red[1]) + (red[2] + red[3]) + b_halt[0]);
  if (p0 >= 0.99f) return;                     // uniform across whole grid
  __syncthreads();

  const int ra = w * HDIM + blockIdx.x * CPB;
  const float za = (lane == 0) ? g_z[ra]     : 0.f;   // only lane0's used
  const float zb = (lane == 0) ? g_z[ra + 1] : 0.f;
  step_body(/*cur=*/1, /*first=*/false,
            reinterpret_cast<const float4*>((const float*)g_h[0]),
            c_in, W_hh, w_halt, za, zb);
}

// ---- dispatch 3: halt decisions + epilogue (+ dead serial fallback) ------
__global__ __launch_bounds__(BT, 4) void fb_final(
    const float* __restrict__ W_hh,  const float* __restrict__ w_halt,
    const float* __restrict__ b_halt, const float* __restrict__ W_out,
    const float* __restrict__ b_out, float* __restrict__ out)
{
  const int tid = threadIdx.x, w = tid >> 6, lane = tid & 63;
  const float bh = b_halt[0];
  __shared__ float red[4];

  // halt decision, bit-identical to fb_step1's (same reduction order)
  float ps = g_part[0][tid]       + g_part[0][tid + 256]
           + g_part[0][tid + 512] + g_part[0][tid + 768];
  ps = wave_reduce(ps);
  if (lane == 0) red[w] = ps;
  __syncthreads();
  const float p0 = sigf((red[0] + red[1]) + (red[2] + red[3]) + bh);
  int tstar = -1;
  float cum = p0;
  if (p0 >= 0.99f) {
    tstar = 0;
  } else {
    __syncthreads();                           // block-uniform branch: safe
    float ps1 = g_part[1][tid]       + g_part[1][tid + 256]
              + g_part[1][tid + 512] + g_part[1][tid + 768];
    ps1 = wave_reduce(ps1);
    if (lane == 0) red[w] = ps1;
    __syncthreads();
    cum = p0 + sigf((red[0] + red[1]) + (red[2] + red[3]) + bh);
    if (cum >= 0.99f) tstar = 1;               // the runtime path
  }

  if (tstar >= 0) {
    // ---- live path: all 1024 blocks ----
    __syncthreads();                           // red[] reuse safety
    const float* hf = g_h[tstar];
    const int r = blockIdx.x;                  // one output row per block
    const float4* Wo4 = reinterpret_cast<const float4*>(W_out)
                        + (size_t)r * (HDIM / 4);
    const float4* hf4 = reinterpret_cast<const float4*>(hf);
    const float4 wv0 = Wo4[tid], wv1 = Wo4[tid + 256];
    const float4 hv0 = hf4[tid], hv1 = hf4[tid + 256];
    float acc = dot4(wv0, hv0) + dot4(wv1, hv1);
    acc = wave_reduce(acc);
    if (lane == 0) red[w] = acc;
    __syncthreads();
    if (tid == 0) out[r] = (red[0] + red[1]) + (red[2] + red[3]) + b_out[r];
    if (tid < CPB) {
      const int j = blockIdx.x * CPB + tid;
      out[1024 + j] = hf[j];                   // h_out
      out[3072 + j] = g_c[j];                  // c_out
    }
    if (blockIdx.x == 0 && tid == CPB) out[5120] = (float)tstar;  // ponder
    return;
  }

  // ---- dead path (never for this data): block 0 finishes serially ----
  if (blockIdx.x != 0) return;
  __shared__ float hs2[HDIM];
  int t_fin = -1;
  for (int s = 2; s < MAXS; ++s) {
    const float* hp = g_h[(s - 1) & 1];
    __syncthreads();
    for (int i = tid; i < HDIM; i += BT) hs2[i] = hp[i];
    __syncthreads();
    float psum = 0.f;
    for (int k = 0; k < HDIM / BT; ++k) {
      const int j = tid + k * BT;
      float gs[4];
      #pragma unroll
      for (int gq = 0; gq < 4; ++gq) {
        const float* Wr = W_hh + (size_t)(gq * HDIM + j) * HDIM;
        float acc = 0.f;
        for (int t = 0; t < HDIM; ++t) acc += Wr[t] * hs2[t];
        gs[gq] = g_z[gq * HDIM + j] + acc;
      }
      const float cn = sigf(gs[1]) * g_c[j] + sigf(gs[0]) * tanhf(gs[2]);
      const float hn = sigf(gs[3]) * tanhf(cn);
      g_c[j] = cn;
      g_h[s & 1][j] = hn;
      psum += w_halt[j] * hn;
    }
    __syncthreads();
    psum = wave_reduce(psum);
    if (lane == 0) red[w] = psum;
    __syncthreads();
    cum += sigf((red[0] + red[1]) + (red[2] + red[3]) + bh);
    if (cum >= 0.99f) { t_fin = s; break; }
  }
  const int t = (t_fin >= 0) ? t_fin : (MAXS - 1);
  const float* hf = g_h[t & 1];
  __syncthreads();
  for (int r = tid; r < ODIM; r += BT) {       // single-block epilogue
    const float* Wr = W_out + (size_t)r * HDIM;
    float acc = 0.f;
    for (int k = 0; k < HDIM; ++k) acc += Wr[k] * hf[k];
    out[r] = acc + b_out[r];
  }
  for (int j = tid; j < HDIM; j += BT) {
    out[1024 + j] = hf[j];
    out[3072 + j] = g_c[j];
  }
  if (tid == 0) out[5120] = (float)t;
}

// ------------------------------------------------------------------- launch
extern "C" void kernel_launch(void* const* d_in, const int* in_sizes, int n_in,
                              void* d_out, int out_size, void* d_ws, size_t ws_size,
                              hipStream_t stream) {
  (void)in_sizes; (void)n_in; (void)d_ws; (void)ws_size; (void)out_size;
  const float* x      = (const float*)d_in[0];
  const float* h      = (const float*)d_in[1];
  const float* c      = (const float*)d_in[2];
  const float* W_ih   = (const float*)d_in[3];
  const float* W_hh   = (const float*)d_in[4];
  const float* b_ih   = (const float*)d_in[5];
  const float* b_hh   = (const float*)d_in[6];
  const float* w_halt = (const float*)d_in[7];
  const float* b_halt = (const float*)d_in[8];
  const float* W_out  = (const float*)d_in[9];
  const float* b_out  = (const float*)d_in[10];
  float* out = (float*)d_out;

  fb_step0<<<dim3(NB), dim3(BT), 0, stream>>>(x, h, c, W_ih, W_hh,
                                              b_ih, b_hh, w_halt);
  fb_step1<<<dim3(NB), dim3(BT), 0, stream>>>(c, W_hh, w_halt, b_halt);
  fb_final<<<dim3(NB), dim3(BT), 0, stream>>>(W_hh, w_halt, b_halt,
                                              W_out, b_out, out);
}